// Round 1
// baseline (105.635 us; speedup 1.0000x reference)
//
#include <hip/hip_runtime.h>
#include <math.h>

#define B 1024
#define O 256
#define D 1024
#define ALPHA 0.005f

#define BT 32          // b-tile per block
#define OT 32          // o-tile per block
#define DC 32          // d-chunk staged in LDS
#define ROW (DC + 4)   // padded LDS row (floats), keeps float4 alignment, breaks pow2 stride

// Kernel A: xd[b][o] = sum_d |x-c|  +  0.5 * sqrt( sum_d (x-c)^2 )
__global__ __launch_bounds__(256) void dist_kernel(const float* __restrict__ x,
                                                   const float* __restrict__ c,
                                                   float* __restrict__ xd)
{
    __shared__ float xs[BT][ROW];
    __shared__ float cs[OT][ROW];

    const int tid = threadIdx.x;
    const int bb  = blockIdx.x * BT;   // base b of tile
    const int ob  = blockIdx.y * OT;   // base o of tile

    // compute layout: tx (o) = tid & 15, ty (b) = tid >> 4; each thread: b∈{ty,ty+16}, o∈{tx,tx+16}
    const int tx = tid & 15;
    const int ty = tid >> 4;

    // staging layout: one float4 per thread per tile: row = tid>>3 (0..31), col = (tid&7)*4
    const int srow = tid >> 3;
    const int scol = (tid & 7) * 4;

    float s1[2][2] = {{0.f, 0.f}, {0.f, 0.f}};
    float s2[2][2] = {{0.f, 0.f}, {0.f, 0.f}};

    const float* xg = &x[(bb + srow) * D + scol];
    const float* cg = &c[(ob + srow) * D + scol];

    for (int d0 = 0; d0 < D; d0 += DC) {
        float4 xv = *(const float4*)(xg + d0);
        float4 cv = *(const float4*)(cg + d0);
        __syncthreads();               // previous chunk's reads done
        *(float4*)&xs[srow][scol] = xv;
        *(float4*)&cs[srow][scol] = cv;
        __syncthreads();               // tile visible

#define ACC(i, j, xv_, cv_)                           \
        {                                             \
            float df_ = (xv_) - (cv_);                \
            s1[i][j] += __builtin_fabsf(df_);         \
            s2[i][j] = __builtin_fmaf(df_, df_, s2[i][j]); \
        }

        #pragma unroll
        for (int d = 0; d < DC; d += 4) {
            float4 xa = *(const float4*)&xs[ty][d];
            float4 xb = *(const float4*)&xs[ty + 16][d];
            float4 ca = *(const float4*)&cs[tx][d];
            float4 cb = *(const float4*)&cs[tx + 16][d];

            ACC(0, 0, xa.x, ca.x); ACC(0, 0, xa.y, ca.y);
            ACC(0, 0, xa.z, ca.z); ACC(0, 0, xa.w, ca.w);

            ACC(0, 1, xa.x, cb.x); ACC(0, 1, xa.y, cb.y);
            ACC(0, 1, xa.z, cb.z); ACC(0, 1, xa.w, cb.w);

            ACC(1, 0, xb.x, ca.x); ACC(1, 0, xb.y, ca.y);
            ACC(1, 0, xb.z, ca.z); ACC(1, 0, xb.w, ca.w);

            ACC(1, 1, xb.x, cb.x); ACC(1, 1, xb.y, cb.y);
            ACC(1, 1, xb.z, cb.z); ACC(1, 1, xb.w, cb.w);
        }
#undef ACC
    }

    // xd = d1/T0 + d2/T1 = s1 + 0.5*sqrt(s2)
    #pragma unroll
    for (int i = 0; i < 2; ++i)
        #pragma unroll
        for (int j = 0; j < 2; ++j) {
            float v = s1[i][j] + 0.5f * __builtin_sqrtf(s2[i][j]);
            xd[(bb + ty + 16 * i) * O + (ob + tx + 16 * j)] = v;
        }
}

// Kernel B: per-row alpha correction.  out = ALPHA*S - (1+ALPHA)*xd,  S = row sum over O
__global__ __launch_bounds__(256) void alpha_kernel(const float* __restrict__ xd,
                                                    float* __restrict__ out)
{
    const int b = blockIdx.x;
    const int o = threadIdx.x;            // 256 threads, one per centroid
    const float v = xd[b * O + o];

    // wave (64-lane) reduction
    float s = v;
    #pragma unroll
    for (int off = 32; off >= 1; off >>= 1)
        s += __shfl_down(s, off, 64);

    __shared__ float ws[4];
    const int lane = o & 63;
    const int w = o >> 6;
    if (lane == 0) ws[w] = s;
    __syncthreads();
    const float S = ws[0] + ws[1] + ws[2] + ws[3];

    out[b * O + o] = ALPHA * S - (1.0f + ALPHA) * v;
}

extern "C" void kernel_launch(void* const* d_in, const int* in_sizes, int n_in,
                              void* d_out, int out_size, void* d_ws, size_t ws_size,
                              hipStream_t stream) {
    const float* x = (const float*)d_in[0];   // [B, D]
    const float* c = (const float*)d_in[1];   // [O, D]
    float* out = (float*)d_out;               // [B, O]
    float* xd  = (float*)d_ws;                // [B, O] scratch (1 MB)

    dim3 grid(B / BT, O / OT);                // (32, 8) = 256 blocks
    dist_kernel<<<grid, 256, 0, stream>>>(x, c, xd);
    alpha_kernel<<<B, 256, 0, stream>>>(xd, out);
}